// Round 9
// baseline (298.558 us; speedup 1.0000x reference)
//
#include <hip/hip_runtime.h>

// GCN layer: segment_sum(x@W^T)[dst] == segment_sum(x)[dst] @ W^T (linearity).
// Round-9: 3 dispatches, zero global atomics, no grid.sync, no srcs/offsets
// arrays (node-sort lives in LDS inside the gather kernel).
//   K1 convert_hist : x->bf16 (+zero row N); LDS hist (98 buckets of 1024
//                     nodes) -> bhistT[bucket*256 + block]
//   K2 bin_scatter  : inline scan (each block derives bucket bases + its
//                     column prefix from bhistT); LDS cursors;
//                     binned[p] = (src<<10)|(dst&1023)
//   K3 sort_gather  : block per 128-node sub-bucket; re-reads its bucket's
//                     binned segment (L2-hot), counting-sorts its ~2K srcs
//                     into LDS, then branchless quad-node gather (4 bf16
//                     dwordx4 row loads in flight, zero-row redirect) +
//                     shfl_xor reduce + readlane @ W^T epilogue.
// Tier D fallback (tiny ws): atomic scatter + LDS linear.

#define DIM 64
#define BN 1024           // nodes per bucket
#define BN_SHIFT 10
#define BN_MASK 1023
#define SUB 128           // nodes per gather block
#define NB_MAX 128        // max buckets
#define BLK1 256          // hist/scatter blocks
#define CAP 6144          // LDS src capacity per gather block (avg ~2048)

__device__ __forceinline__ unsigned short f32_to_bf16_rne(float f) {
    unsigned u = __float_as_uint(f);
    unsigned r = u + 0x7FFFu + ((u >> 16) & 1u);
    return (unsigned short)(r >> 16);
}

// ---------------------------------------------------------------------------
// K1: convert x -> bf16 (incl. zero row N) + per-block LDS histogram.
__global__ __launch_bounds__(256) void convert_hist_kernel(
        const float* __restrict__ x, const int* __restrict__ ei,
        ushort4* __restrict__ xb4, int* __restrict__ bhistT,
        int E, int N, int nb, int total4) {
    __shared__ int h[NB_MAX];
    const int t = threadIdx.x;
    const int bid = blockIdx.x;

    for (int b = t; b < nb; b += 256) h[b] = 0;

    for (int i = bid * 256 + t; i < total4; i += BLK1 * 256) {
        float4 v = ((const float4*)x)[i];
        ushort4 o;
        o.x = f32_to_bf16_rne(v.x); o.y = f32_to_bf16_rne(v.y);
        o.z = f32_to_bf16_rne(v.z); o.w = f32_to_bf16_rne(v.w);
        xb4[i] = o;
    }
    if (bid == 0 && t < 16) {                 // zero row N
        ushort4 z; z.x = 0; z.y = 0; z.z = 0; z.w = 0;
        xb4[(size_t)N * 16 + t] = z;
    }
    __syncthreads();

    for (int e = bid * 256 + t; e < E; e += BLK1 * 256)
        atomicAdd(&h[ei[E + e] >> BN_SHIFT], 1);
    __syncthreads();
    for (int b = t; b < nb; b += 256)
        bhistT[b * BLK1 + bid] = h[b];
}

// ---------------------------------------------------------------------------
// K2: bin_scatter with inline scan. Block bid derives its own cursors:
// cur[b] = (sum of tot[j] for j<b) + (sum of bhistT[b][blk] for blk<bid).
__global__ __launch_bounds__(256) void bin_scatter_kernel(
        const int* __restrict__ ei, const int* __restrict__ bhistT,
        int* __restrict__ binned, int E, int nb) {
    __shared__ int tot[NB_MAX];
    __shared__ int part[NB_MAX];
    __shared__ int curs[NB_MAX];
    const int t = threadIdx.x;
    const int bid = blockIdx.x;

    if (t < nb) {
        const int* row = bhistT + (size_t)t * BLK1;
        int s = 0, p = 0;
        for (int k = 0; k < BLK1; ++k) {
            int v = row[k];
            s += v;
            if (k < bid) p += v;
        }
        tot[t] = s; part[t] = p;
    }
    __syncthreads();
    if (t == 0) {
        int run = 0;
        for (int j = 0; j < nb; ++j) { curs[j] = run + part[j]; run += tot[j]; }
    }
    __syncthreads();

    for (int e = bid * 256 + t; e < E; e += BLK1 * 256) {
        int s = ei[e];
        int d = ei[E + e];
        int p = atomicAdd(&curs[d >> BN_SHIFT], 1);
        binned[p] = (s << BN_SHIFT) | (d & BN_MASK);
    }
}

// ---------------------------------------------------------------------------
// Gather helpers (proven in round 8).
__device__ __forceinline__ void acc8(float (&a)[8], const uint4& v) {
    a[0] += __uint_as_float(v.x << 16); a[1] += __uint_as_float(v.x & 0xFFFF0000u);
    a[2] += __uint_as_float(v.y << 16); a[3] += __uint_as_float(v.y & 0xFFFF0000u);
    a[4] += __uint_as_float(v.z << 16); a[5] += __uint_as_float(v.z & 0xFFFF0000u);
    a[6] += __uint_as_float(v.w << 16); a[7] += __uint_as_float(v.w & 0xFFFF0000u);
}

__device__ __forceinline__ float epilogue64(const float (&a)[8],
                                            const float (&wv)[DIM], float bb) {
    float r0 = bb, r1 = 0.f, r2 = 0.f, r3 = 0.f;
    #pragma unroll
    for (int k = 0; k < DIM; k += 4) {
        r0 += __int_as_float(__builtin_amdgcn_readlane(
                  __float_as_int(a[(k + 0) & 7]), (k + 0) >> 3)) * wv[k + 0];
        r1 += __int_as_float(__builtin_amdgcn_readlane(
                  __float_as_int(a[(k + 1) & 7]), (k + 1) >> 3)) * wv[k + 1];
        r2 += __int_as_float(__builtin_amdgcn_readlane(
                  __float_as_int(a[(k + 2) & 7]), (k + 2) >> 3)) * wv[k + 2];
        r3 += __int_as_float(__builtin_amdgcn_readlane(
                  __float_as_int(a[(k + 3) & 7]), (k + 3) >> 3)) * wv[k + 3];
    }
    return (r0 + r1) + (r2 + r3);
}

// ---------------------------------------------------------------------------
// K3: fused LDS counting-sort + branchless quad gather.
// Block g covers nodes [g*128, g*128+128); bucket b = g>>3, sub = g&7.
__global__ __launch_bounds__(256) void sort_gather_kernel(
        const unsigned short* __restrict__ xh, const int* __restrict__ binned,
        const int* __restrict__ bhistT, const float* __restrict__ W,
        const float* __restrict__ bias, float* __restrict__ out,
        int N, int nb) {
    __shared__ int tot[NB_MAX];
    __shared__ int segs[2];              // seg0, seg1
    __shared__ int cnt[SUB];
    __shared__ int basel[SUB + 1];
    __shared__ int pref[SUB];
    __shared__ int slds[CAP];

    const int t = threadIdx.x;
    const int g = blockIdx.x;
    const int b = g >> 3;
    const int sub = g & 7;
    const int node0 = g << 7;

    // W row `lane` + bias (loaded early; overlaps with scan/sort)
    const int lane = t & 63;
    const int wid = t >> 6;
    float wv[DIM];
    #pragma unroll
    for (int k4 = 0; k4 < DIM / 4; ++k4) {
        float4 tw = *(const float4*)(W + (size_t)lane * DIM + k4 * 4);
        wv[k4 * 4 + 0] = tw.x; wv[k4 * 4 + 1] = tw.y;
        wv[k4 * 4 + 2] = tw.z; wv[k4 * 4 + 3] = tw.w;
    }
    const float bb = bias[lane];

    // bucket totals -> segment bounds for bucket b
    if (t < nb) {
        const int4* row = (const int4*)(bhistT + (size_t)t * BLK1);
        int s = 0;
        #pragma unroll 8
        for (int k = 0; k < BLK1 / 4; ++k) {
            int4 v = row[k];
            s += v.x + v.y + v.z + v.w;
        }
        tot[t] = s;
    }
    __syncthreads();
    if (t == 0) {
        int run = 0;
        for (int j = 0; j < nb; ++j) {
            if (j == b) segs[0] = run;
            run += tot[j];
            if (j == b) segs[1] = run;
        }
    }
    if (t < SUB) cnt[t] = 0;
    __syncthreads();
    const int seg0 = segs[0], seg1 = segs[1];

    // pass 1: count this sub-block's nodes
    for (int i = seg0 + t; i < seg1; i += 256) {
        int v = binned[i];
        int d = v & BN_MASK;
        if ((d >> 7) == sub) atomicAdd(&cnt[d & 127], 1);
    }
    __syncthreads();

    // exclusive prefix over 128 counters
    int myv = (t < SUB) ? cnt[t] : 0;
    if (t < SUB) pref[t] = myv;
    __syncthreads();
    #pragma unroll
    for (int d = 1; d < SUB; d <<= 1) {
        int u = (t < SUB && t >= d) ? pref[t - d] : 0;
        __syncthreads();
        if (t < SUB) pref[t] += u;
        __syncthreads();
    }
    if (t < SUB) basel[t] = pref[t] - myv;
    if (t == SUB - 1) basel[SUB] = pref[t];
    __syncthreads();
    const int total = basel[SUB];

    if (total <= CAP) {
        // pass 2: scatter srcs into LDS
        if (t < SUB) cnt[t] = basel[t];
        __syncthreads();
        for (int i = seg0 + t; i < seg1; i += 256) {
            int v = binned[i];
            int d = v & BN_MASK;
            if ((d >> 7) == sub) {
                int p = atomicAdd(&cnt[d & 127], 1);
                slds[p] = v >> BN_SHIFT;
            }
        }
        __syncthreads();

        // branchless quad gather from LDS src lists
        const int sub8 = lane >> 3;
        const int fb   = (lane & 7) << 3;
        const int zrow = N;
        for (int q = wid; q < (SUB >> 2); q += 4) {
            const int nl = q << 2;
            int b0 = basel[nl + 0], e0 = basel[nl + 1];
            int b1 = basel[nl + 1], e1 = basel[nl + 2];
            int b2 = basel[nl + 2], e2 = basel[nl + 3];
            int b3 = basel[nl + 3], e3 = basel[nl + 4];
            int c0 = (e0 - b0 + 7) >> 3, c1 = (e1 - b1 + 7) >> 3;
            int c2 = (e2 - b2 + 7) >> 3, c3 = (e3 - b3 + 7) >> 3;
            int cmax = max(max(c0, c1), max(c2, c3));
            cmax = __builtin_amdgcn_readfirstlane(cmax);

            float A0[8] = {0.f,0.f,0.f,0.f,0.f,0.f,0.f,0.f};
            float A1[8] = {0.f,0.f,0.f,0.f,0.f,0.f,0.f,0.f};
            float A2[8] = {0.f,0.f,0.f,0.f,0.f,0.f,0.f,0.f};
            float A3[8] = {0.f,0.f,0.f,0.f,0.f,0.f,0.f,0.f};

            for (int c = 0; c < cmax; ++c) {
                const int o = (c << 3) + sub8;
                int i0 = b0 + o, i1 = b1 + o, i2 = b2 + o, i3 = b3 + o;
                int s0 = slds[min(i0, CAP - 1)];
                int s1 = slds[min(i1, CAP - 1)];
                int s2 = slds[min(i2, CAP - 1)];
                int s3 = slds[min(i3, CAP - 1)];
                s0 = (i0 < e0) ? s0 : zrow;
                s1 = (i1 < e1) ? s1 : zrow;
                s2 = (i2 < e2) ? s2 : zrow;
                s3 = (i3 < e3) ? s3 : zrow;
                uint4 v0 = *(const uint4*)(xh + (size_t)s0 * DIM + fb);
                uint4 v1 = *(const uint4*)(xh + (size_t)s1 * DIM + fb);
                uint4 v2 = *(const uint4*)(xh + (size_t)s2 * DIM + fb);
                uint4 v3 = *(const uint4*)(xh + (size_t)s3 * DIM + fb);
                acc8(A0, v0); acc8(A1, v1); acc8(A2, v2); acc8(A3, v3);
            }

            #pragma unroll
            for (int d = 8; d <= 32; d <<= 1) {
                #pragma unroll
                for (int j = 0; j < 8; ++j) {
                    A0[j] += __shfl_xor(A0[j], d, 64);
                    A1[j] += __shfl_xor(A1[j], d, 64);
                    A2[j] += __shfl_xor(A2[j], d, 64);
                    A3[j] += __shfl_xor(A3[j], d, 64);
                }
            }

            const int n0 = node0 + nl;
            if (n0 + 0 < N) out[(size_t)(n0 + 0) * DIM + lane] = epilogue64(A0, wv, bb);
            if (n0 + 1 < N) out[(size_t)(n0 + 1) * DIM + lane] = epilogue64(A1, wv, bb);
            if (n0 + 2 < N) out[(size_t)(n0 + 2) * DIM + lane] = epilogue64(A2, wv, bb);
            if (n0 + 3 < N) out[(size_t)(n0 + 3) * DIM + lane] = epilogue64(A3, wv, bb);
        }
    } else {
        // slow path (LDS overflow; never expected for uniform graphs):
        // one wave per node, scan the whole bucket segment.
        for (int q = wid; q < SUB; q += 4) {
            int node = node0 + q;
            if (node >= N) continue;
            int target = (sub << 7) | q;
            float acc = 0.f;
            for (int i = seg0; i < seg1; ++i) {
                int v = binned[i];
                if ((v & BN_MASK) == target) {
                    unsigned short hh = xh[(size_t)(v >> BN_SHIFT) * DIM + lane];
                    acc += __uint_as_float((unsigned)hh << 16);
                }
            }
            float r0 = bb, r1 = 0.f, r2 = 0.f, r3 = 0.f;
            #pragma unroll
            for (int k = 0; k < DIM; k += 4) {
                r0 += __int_as_float(__builtin_amdgcn_readlane(__float_as_int(acc), k + 0)) * wv[k + 0];
                r1 += __int_as_float(__builtin_amdgcn_readlane(__float_as_int(acc), k + 1)) * wv[k + 1];
                r2 += __int_as_float(__builtin_amdgcn_readlane(__float_as_int(acc), k + 2)) * wv[k + 2];
                r3 += __int_as_float(__builtin_amdgcn_readlane(__float_as_int(acc), k + 3)) * wv[k + 3];
            }
            out[(size_t)node * DIM + lane] = (r0 + r1) + (r2 + r3);
        }
    }
}

// ------------------- tier D: atomic scatter fallback -----------------------
__global__ void gcn_scatter_kernel(const float* __restrict__ x,
                                   const int* __restrict__ edge_index,
                                   float* __restrict__ out, int n_edges) {
    int gid = blockIdx.x * blockDim.x + threadIdx.x;
    int e = gid >> 4;
    if (e >= n_edges) return;
    int j = (gid & 15) << 2;
    int src = edge_index[e];
    int dst = edge_index[n_edges + e];
    const float4 v = *(const float4*)(x + (size_t)src * DIM + j);
    float* o = out + (size_t)dst * DIM + j;
    atomicAdd(o + 0, v.x); atomicAdd(o + 1, v.y);
    atomicAdd(o + 2, v.z); atomicAdd(o + 3, v.w);
}

__global__ void gcn_linear_inplace_kernel(float* __restrict__ out,
                                          const float* __restrict__ W,
                                          const float* __restrict__ bias,
                                          int n_nodes) {
    __shared__ float Wt[DIM * DIM];
    __shared__ float rows[4][DIM];
    int tid = threadIdx.x;
    int col = tid & 63;
    int r = tid >> 6;
    for (int i = tid; i < DIM * DIM; i += 256) {
        int c = i >> 6, k = i & 63;
        Wt[k * DIM + c] = W[i];
    }
    int row = blockIdx.x * 4 + r;
    if (row < n_nodes) rows[r][col] = out[(size_t)row * DIM + col];
    __syncthreads();
    if (row < n_nodes) {
        float a = 0.f;
        #pragma unroll
        for (int k = 0; k < DIM; ++k) a += rows[r][k] * Wt[k * DIM + col];
        out[(size_t)row * DIM + col] = a + bias[col];
    }
}

// ===========================================================================
extern "C" void kernel_launch(void* const* d_in, const int* in_sizes, int n_in,
                              void* d_out, int out_size, void* d_ws, size_t ws_size,
                              hipStream_t stream) {
    const float* x          = (const float*)d_in[0];   // [N, 64]
    const float* W          = (const float*)d_in[1];   // [64, 64]
    const float* bias       = (const float*)d_in[2];   // [64]
    const int*   edge_index = (const int*)d_in[3];     // [2, E] (int32)

    const int E = in_sizes[3] / 2;
    const int N = in_sizes[0] / DIM;
    float* out = (float*)d_out;

    const int nb = (N + BN - 1) >> BN_SHIFT;
    const int block = 256;

    auto align256 = [](size_t v) { return (v + 255) & ~(size_t)255; };
    const size_t xb_b   = align256(((size_t)N + 1) * DIM * 2);   // +1 zero row
    const size_t bin_b  = align256((size_t)E * 4);
    const size_t hist_b = align256((size_t)nb * BLK1 * 4);
    const size_t needA = xb_b + bin_b + hist_b;

    if (nb <= NB_MAX && N < (1 << 17) && ws_size >= needA) {
        char* p = (char*)d_ws;
        ushort4* xb4 = (ushort4*)p;          p += xb_b;
        int* binned  = (int*)p;              p += bin_b;
        int* bhistT  = (int*)p;

        const int total4 = N * DIM / 4;

        convert_hist_kernel<<<BLK1, block, 0, stream>>>(
            x, edge_index, xb4, bhistT, E, N, nb, total4);
        bin_scatter_kernel<<<BLK1, block, 0, stream>>>(
            edge_index, bhistT, binned, E, nb);
        const int gblocks = (N + SUB - 1) >> 7;
        sort_gather_kernel<<<gblocks, block, 0, stream>>>(
            (const unsigned short*)xb4, binned, bhistT, W, bias, out, N, nb);
    } else {
        hipMemsetAsync(d_out, 0, (size_t)out_size * sizeof(float), stream);
        long long total = (long long)E * 16;
        int grid = (int)((total + block - 1) / block);
        gcn_scatter_kernel<<<grid, block, 0, stream>>>(x, edge_index, out, E);
        int lgrid = (N + 3) / 4;
        gcn_linear_inplace_kernel<<<lgrid, 256, 0, stream>>>(out, W, bias, N);
    }
}

// Round 10
// 255.010 us; speedup vs baseline: 1.1708x; 1.1708x over previous
//
#include <hip/hip_runtime.h>

// GCN layer: segment_sum(x@W^T)[dst] == segment_sum(x)[dst] @ W^T (linearity).
// Round-10: 4 dispatches, zero global atomics on the fast path.
//   K1 hist           : read dst only; LDS hist over nb=ceil(N/256) buckets
//                       -> bhistT[bucket*PB + block]          (~8 us)
//   K2 convert_scatter: x->bf16 (+zero row) FUSED with inline scan
//                       (block derives bucket bases + own column prefix) and
//                       LDS-cursor scatter: binned[p]=(src<<8)|(dst&255)
//   K3 bucket_sort    : 391 blocks (256-node buckets), inline totals scan,
//                       256 LDS counters -> exact CSR (offsets, srcs)
//   K4 gather_quad    : r8's proven branchless quad gather (4 bf16 dwordx4
//                       row loads in flight, zero-row redirect, shfl_xor
//                       reduce, readlane @ W^T epilogue)
// Tier D fallback (tiny ws): atomic scatter + LDS linear.

#define DIM 64
#define BN 256            // nodes per bucket
#define BN_SHIFT 8
#define BN_MASK 255
#define NB_MAX 512        // max buckets (LDS capacity)
#define PB 128            // hist/scatter blocks (32-edge = 128B runs/bucket)

__device__ __forceinline__ unsigned short f32_to_bf16_rne(float f) {
    unsigned u = __float_as_uint(f);
    unsigned r = u + 0x7FFFu + ((u >> 16) & 1u);
    return (unsigned short)(r >> 16);
}

// ---------------------------------------------------------------------------
// K1: per-block LDS histogram of dst buckets.
__global__ __launch_bounds__(256) void hist_kernel(
        const int* __restrict__ ei, int* __restrict__ bhistT, int E, int nb) {
    __shared__ int h[NB_MAX];
    const int t = threadIdx.x;
    const int bid = blockIdx.x;
    for (int b = t; b < nb; b += 256) h[b] = 0;
    __syncthreads();
    for (int e = bid * 256 + t; e < E; e += PB * 256)
        atomicAdd(&h[ei[E + e] >> BN_SHIFT], 1);
    __syncthreads();
    for (int b = t; b < nb; b += 256)
        bhistT[b * PB + bid] = h[b];
}

// ---------------------------------------------------------------------------
// K2: convert x->bf16 (+zero row N) fused with inline-scan bin_scatter.
// cursors: curs[b] = sum_{j<b} tot[j] + sum_{k<bid} bhistT[b][k].
__global__ __launch_bounds__(256) void convert_scatter_kernel(
        const float* __restrict__ x, const int* __restrict__ ei,
        const int* __restrict__ bhistT, ushort4* __restrict__ xb4,
        int* __restrict__ binned, int E, int N, int nb, int total4) {
    __shared__ int tot[NB_MAX];
    __shared__ int part[NB_MAX];
    __shared__ int curs[NB_MAX];
    const int t = threadIdx.x;
    const int bid = blockIdx.x;

    // convert (independent of hist/scan; overlaps)
    for (int i = bid * 256 + t; i < total4; i += PB * 256) {
        float4 v = ((const float4*)x)[i];
        ushort4 o;
        o.x = f32_to_bf16_rne(v.x); o.y = f32_to_bf16_rne(v.y);
        o.z = f32_to_bf16_rne(v.z); o.w = f32_to_bf16_rne(v.w);
        xb4[i] = o;
    }
    if (bid == 0 && t < 16) {                 // zero row N
        ushort4 z; z.x = 0; z.y = 0; z.z = 0; z.w = 0;
        xb4[(size_t)N * 16 + t] = z;
    }

    // inline scan: totals + partial-before-bid per bucket
    for (int b = t; b < nb; b += 256) {
        const int* row = bhistT + (size_t)b * PB;
        int s = 0, p = 0;
        #pragma unroll 8
        for (int k = 0; k < PB; ++k) {
            int v = row[k];
            s += v;
            if (k < bid) p += v;
        }
        tot[b] = s; part[b] = p;
    }
    __syncthreads();
    if (t == 0) {
        int run = 0;
        for (int j = 0; j < nb; ++j) { curs[j] = run + part[j]; run += tot[j]; }
    }
    __syncthreads();

    // scatter
    for (int e = bid * 256 + t; e < E; e += PB * 256) {
        int s = ei[e];
        int d = ei[E + e];
        int p = atomicAdd(&curs[d >> BN_SHIFT], 1);
        binned[p] = (s << BN_SHIFT) | (d & BN_MASK);
    }
}

// ---------------------------------------------------------------------------
// K3: block per 256-node bucket; inline totals scan; counting sort -> CSR.
__global__ __launch_bounds__(256) void bucket_sort_kernel(
        const int* __restrict__ binned, const int* __restrict__ bhistT,
        int* __restrict__ srcs, int* __restrict__ offsets, int E, int N, int nb) {
    __shared__ int tot[NB_MAX];
    __shared__ int segs[2];
    __shared__ int cnt[BN];
    __shared__ int basel[BN + 1];
    __shared__ int tmp[256];
    const int t = threadIdx.x;
    const int b = blockIdx.x;

    // bucket totals
    for (int j = t; j < nb; j += 256) {
        const int4* row = (const int4*)(bhistT + (size_t)j * PB);
        int s = 0;
        #pragma unroll 8
        for (int k = 0; k < PB / 4; ++k) {
            int4 v = row[k];
            s += v.x + v.y + v.z + v.w;
        }
        tot[j] = s;
    }
    __syncthreads();
    if (t == 0) {
        int run = 0;
        for (int j = 0; j < b; ++j) run += tot[j];
        segs[0] = run;
        segs[1] = run + tot[b];
    }
    cnt[t] = 0;
    __syncthreads();
    const int seg0 = segs[0], seg1 = segs[1];

    // pass 1: count per-node
    for (int i = seg0 + t; i < seg1; i += 256)
        atomicAdd(&cnt[binned[i] & BN_MASK], 1);
    __syncthreads();

    // exclusive prefix over 256 counters
    int myv = cnt[t];
    tmp[t] = myv;
    __syncthreads();
    #pragma unroll
    for (int d = 1; d < 256; d <<= 1) {
        int u = (t >= d) ? tmp[t - d] : 0;
        __syncthreads();
        tmp[t] += u;
        __syncthreads();
    }
    basel[t] = tmp[t] - myv;
    if (t == 255) basel[256] = tmp[255];
    __syncthreads();

    const int node0 = b << BN_SHIFT;
    if (node0 + t < N) offsets[node0 + t] = seg0 + basel[t];
    if (b == 0 && t == 0) offsets[N] = E;
    cnt[t] = basel[t];                        // cursors
    __syncthreads();

    // pass 2: scatter srcs (L2-hot re-read, ~16KB window)
    for (int i = seg0 + t; i < seg1; i += 256) {
        int v = binned[i];
        int p = atomicAdd(&cnt[v & BN_MASK], 1);
        srcs[seg0 + p] = v >> BN_SHIFT;
    }
}

// ---------------------------------------------------------------------------
// K4: branchless quad gather (r8, proven).
__device__ __forceinline__ void acc8(float (&a)[8], const uint4& v) {
    a[0] += __uint_as_float(v.x << 16); a[1] += __uint_as_float(v.x & 0xFFFF0000u);
    a[2] += __uint_as_float(v.y << 16); a[3] += __uint_as_float(v.y & 0xFFFF0000u);
    a[4] += __uint_as_float(v.z << 16); a[5] += __uint_as_float(v.z & 0xFFFF0000u);
    a[6] += __uint_as_float(v.w << 16); a[7] += __uint_as_float(v.w & 0xFFFF0000u);
}

__device__ __forceinline__ float epilogue64(const float (&a)[8],
                                            const float (&wv)[DIM], float bb) {
    float r0 = bb, r1 = 0.f, r2 = 0.f, r3 = 0.f;
    #pragma unroll
    for (int k = 0; k < DIM; k += 4) {
        r0 += __int_as_float(__builtin_amdgcn_readlane(
                  __float_as_int(a[(k + 0) & 7]), (k + 0) >> 3)) * wv[k + 0];
        r1 += __int_as_float(__builtin_amdgcn_readlane(
                  __float_as_int(a[(k + 1) & 7]), (k + 1) >> 3)) * wv[k + 1];
        r2 += __int_as_float(__builtin_amdgcn_readlane(
                  __float_as_int(a[(k + 2) & 7]), (k + 2) >> 3)) * wv[k + 2];
        r3 += __int_as_float(__builtin_amdgcn_readlane(
                  __float_as_int(a[(k + 3) & 7]), (k + 3) >> 3)) * wv[k + 3];
    }
    return (r0 + r1) + (r2 + r3);
}

__global__ __launch_bounds__(256) void gather_quad_kernel(
        const unsigned short* __restrict__ xh, const int* __restrict__ offsets,
        const int* __restrict__ srcs, const float* __restrict__ W,
        const float* __restrict__ bias, float* __restrict__ out,
        int n_nodes, int E) {
    const int lane = threadIdx.x & 63;
    const int sub  = lane >> 3;
    const int fb   = (lane & 7) << 3;
    const int gwave = (blockIdx.x * blockDim.x + threadIdx.x) >> 6;
    const int total_waves = (gridDim.x * blockDim.x) >> 6;
    const int zrow = n_nodes;
    const int slast = E + 48;

    float wv[DIM];
    #pragma unroll
    for (int k4 = 0; k4 < DIM / 4; ++k4) {
        float4 tw = *(const float4*)(W + (size_t)lane * DIM + k4 * 4);
        wv[k4 * 4 + 0] = tw.x; wv[k4 * 4 + 1] = tw.y;
        wv[k4 * 4 + 2] = tw.z; wv[k4 * 4 + 3] = tw.w;
    }
    const float bb = bias[lane];

    const int quads = (n_nodes + 3) >> 2;
    for (int q = gwave; q < quads; q += total_waves) {
        const int n0 = q << 2;
        int b0 = offsets[n0], e0 = offsets[n0 + 1];
        int b1 = 0, e1 = 0, b2 = 0, e2 = 0, b3 = 0, e3 = 0;
        if (n0 + 1 < n_nodes) { b1 = e0; e1 = offsets[n0 + 2]; }
        if (n0 + 2 < n_nodes) { b2 = e1; e2 = offsets[n0 + 3]; }
        if (n0 + 3 < n_nodes) { b3 = e2; e3 = offsets[n0 + 4]; }
        int c0 = (e0 - b0 + 7) >> 3, c1 = (e1 - b1 + 7) >> 3;
        int c2 = (e2 - b2 + 7) >> 3, c3 = (e3 - b3 + 7) >> 3;
        int cmax = max(max(c0, c1), max(c2, c3));
        cmax = __builtin_amdgcn_readfirstlane(cmax);

        float A0[8] = {0.f,0.f,0.f,0.f,0.f,0.f,0.f,0.f};
        float A1[8] = {0.f,0.f,0.f,0.f,0.f,0.f,0.f,0.f};
        float A2[8] = {0.f,0.f,0.f,0.f,0.f,0.f,0.f,0.f};
        float A3[8] = {0.f,0.f,0.f,0.f,0.f,0.f,0.f,0.f};

        for (int c = 0; c < cmax; ++c) {
            const int o = (c << 3) + sub;
            int i0 = b0 + o, i1 = b1 + o, i2 = b2 + o, i3 = b3 + o;
            int s0 = srcs[min(i0, slast)];
            int s1 = srcs[min(i1, slast)];
            int s2 = srcs[min(i2, slast)];
            int s3 = srcs[min(i3, slast)];
            s0 = (i0 < e0) ? s0 : zrow;
            s1 = (i1 < e1) ? s1 : zrow;
            s2 = (i2 < e2) ? s2 : zrow;
            s3 = (i3 < e3) ? s3 : zrow;
            uint4 v0 = *(const uint4*)(xh + (size_t)s0 * DIM + fb);
            uint4 v1 = *(const uint4*)(xh + (size_t)s1 * DIM + fb);
            uint4 v2 = *(const uint4*)(xh + (size_t)s2 * DIM + fb);
            uint4 v3 = *(const uint4*)(xh + (size_t)s3 * DIM + fb);
            acc8(A0, v0); acc8(A1, v1); acc8(A2, v2); acc8(A3, v3);
        }

        #pragma unroll
        for (int d = 8; d <= 32; d <<= 1) {
            #pragma unroll
            for (int j = 0; j < 8; ++j) {
                A0[j] += __shfl_xor(A0[j], d, 64);
                A1[j] += __shfl_xor(A1[j], d, 64);
                A2[j] += __shfl_xor(A2[j], d, 64);
                A3[j] += __shfl_xor(A3[j], d, 64);
            }
        }

        out[(size_t)n0 * DIM + lane] = epilogue64(A0, wv, bb);
        if (n0 + 1 < n_nodes) out[(size_t)(n0 + 1) * DIM + lane] = epilogue64(A1, wv, bb);
        if (n0 + 2 < n_nodes) out[(size_t)(n0 + 2) * DIM + lane] = epilogue64(A2, wv, bb);
        if (n0 + 3 < n_nodes) out[(size_t)(n0 + 3) * DIM + lane] = epilogue64(A3, wv, bb);
    }
}

// ------------------- tier D: atomic scatter fallback -----------------------
__global__ void gcn_scatter_kernel(const float* __restrict__ x,
                                   const int* __restrict__ edge_index,
                                   float* __restrict__ out, int n_edges) {
    int gid = blockIdx.x * blockDim.x + threadIdx.x;
    int e = gid >> 4;
    if (e >= n_edges) return;
    int j = (gid & 15) << 2;
    int src = edge_index[e];
    int dst = edge_index[n_edges + e];
    const float4 v = *(const float4*)(x + (size_t)src * DIM + j);
    float* o = out + (size_t)dst * DIM + j;
    atomicAdd(o + 0, v.x); atomicAdd(o + 1, v.y);
    atomicAdd(o + 2, v.z); atomicAdd(o + 3, v.w);
}

__global__ void gcn_linear_inplace_kernel(float* __restrict__ out,
                                          const float* __restrict__ W,
                                          const float* __restrict__ bias,
                                          int n_nodes) {
    __shared__ float Wt[DIM * DIM];
    __shared__ float rows[4][DIM];
    int tid = threadIdx.x;
    int col = tid & 63;
    int r = tid >> 6;
    for (int i = tid; i < DIM * DIM; i += 256) {
        int c = i >> 6, k = i & 63;
        Wt[k * DIM + c] = W[i];
    }
    int row = blockIdx.x * 4 + r;
    if (row < n_nodes) rows[r][col] = out[(size_t)row * DIM + col];
    __syncthreads();
    if (row < n_nodes) {
        float a = 0.f;
        #pragma unroll
        for (int k = 0; k < DIM; ++k) a += rows[r][k] * Wt[k * DIM + col];
        out[(size_t)row * DIM + col] = a + bias[col];
    }
}

// ===========================================================================
extern "C" void kernel_launch(void* const* d_in, const int* in_sizes, int n_in,
                              void* d_out, int out_size, void* d_ws, size_t ws_size,
                              hipStream_t stream) {
    const float* x          = (const float*)d_in[0];   // [N, 64]
    const float* W          = (const float*)d_in[1];   // [64, 64]
    const float* bias       = (const float*)d_in[2];   // [64]
    const int*   edge_index = (const int*)d_in[3];     // [2, E] (int32)

    const int E = in_sizes[3] / 2;
    const int N = in_sizes[0] / DIM;
    float* out = (float*)d_out;

    const int nb = (N + BN - 1) >> BN_SHIFT;
    const int block = 256;

    auto align256 = [](size_t v) { return (v + 255) & ~(size_t)255; };
    const size_t xb_b   = align256(((size_t)N + 1) * DIM * 2);   // +1 zero row
    const size_t bin_b  = align256((size_t)E * 4);
    const size_t hist_b = align256((size_t)nb * PB * 4);
    const size_t srcs_b = align256(((size_t)E + 64) * 4);
    const size_t offs_b = align256(((size_t)N + 1) * 4);
    const size_t needA = xb_b + bin_b + hist_b + srcs_b + offs_b;

    // src must fit in 24 bits for the (src<<8)|dstlo packing
    if (nb <= NB_MAX && N < (1 << 24) && ws_size >= needA) {
        char* p = (char*)d_ws;
        ushort4* xb4 = (ushort4*)p;          p += xb_b;
        int* binned  = (int*)p;              p += bin_b;
        int* bhistT  = (int*)p;              p += hist_b;
        int* srcs    = (int*)p;              p += srcs_b;
        int* offsets = (int*)p;

        const int total4 = N * DIM / 4;

        hist_kernel<<<PB, block, 0, stream>>>(edge_index, bhistT, E, nb);
        convert_scatter_kernel<<<PB, block, 0, stream>>>(
            x, edge_index, bhistT, xb4, binned, E, N, nb, total4);
        bucket_sort_kernel<<<nb, block, 0, stream>>>(
            binned, bhistT, srcs, offsets, E, N, nb);

        const int quads = (N + 3) >> 2;
        const int gblocks = (quads + 7) / 8;     // ~2 quads per wave
        gather_quad_kernel<<<gblocks, block, 0, stream>>>(
            (const unsigned short*)xb4, offsets, srcs, W, bias, out, N, E);
    } else {
        hipMemsetAsync(d_out, 0, (size_t)out_size * sizeof(float), stream);
        long long total = (long long)E * 16;
        int grid = (int)((total + block - 1) / block);
        gcn_scatter_kernel<<<grid, block, 0, stream>>>(x, edge_index, out, E);
        int lgrid = (N + 3) / 4;
        gcn_linear_inplace_kernel<<<lgrid, 256, 0, stream>>>(out, W, bias, N);
    }
}